// Round 9
// baseline (298.280 us; speedup 1.0000x reference)
//
#include <hip/hip_runtime.h>
#include <math.h>

// BalancedLoss: B=65536 rows, C=512 classes, pos_prop per class.
// loss = mean(bce(pred,target) * w), w depends only on (column, target value).
//
// History: R1 147us (libm VALU-bound) -> R3 107us (fast softplus, striped
// atomics) -> R4/R5/R6 (stores/reg-batch/LDS-DMA) all pinned at ~105us ->
// R8 (block 256, grid 2048, nontemporal loads): partial <=77us, total 271.
// ~185us of the total is fixed harness reset (d_in restore + 536MB ws poison
// at 6.9 TB/s write). Platform read path: copy read-side ~3.15 TB/s (m13),
// our stream 3.2-3.5+ TB/s -- near the demonstrated read ceiling.
// R9: discriminate the last lever: grid 2048->4096 (more block streams; if
// nt/L1-bypass was the R8 lever this is neutral) + rebuild bl_reduce as 128
// blocks x 256 thr (col-quad per block) to cut its latency-serial tail.

constexpr int C = 512;
constexpr int C4 = 128;          // float4s per row
constexpr int PSTRIDE = 3 * C;   // 1536 floats per partial slot

typedef float floatv4 __attribute__((ext_vector_type(4)));

__device__ __forceinline__ float softplus_neg_abs(float p) {
    // log(1 + exp(-|p|)) via v_exp/v_log; arg in (1,2], abs err ~1e-7.
    return __logf(1.0f + __expf(-fabsf(p)));
}

__device__ __forceinline__ float4 ntload(const float4* p) {
    floatv4 v = __builtin_nontemporal_load((const floatv4*)p);
    return make_float4(v.x, v.y, v.z, v.w);
}

__device__ __forceinline__ void acc4(const float4& p, const float4& t,
                                     float4& a_s1, float4& a_st, float4& a_c1) {
    float b;
    b = fmaxf(p.x, 0.f) + softplus_neg_abs(p.x) - p.x * t.x;
    a_st.x += b; a_s1.x += b * t.x; a_c1.x += t.x;
    b = fmaxf(p.y, 0.f) + softplus_neg_abs(p.y) - p.y * t.y;
    a_st.y += b; a_s1.y += b * t.y; a_c1.y += t.y;
    b = fmaxf(p.z, 0.f) + softplus_neg_abs(p.z) - p.z * t.z;
    a_st.z += b; a_s1.z += b * t.z; a_c1.z += t.z;
    b = fmaxf(p.w, 0.f) + softplus_neg_abs(p.w) - p.w * t.w;
    a_st.w += b; a_s1.w += b * t.w; a_c1.w += t.w;
}

__global__ __launch_bounds__(256, 8) void bl_partial(
    const float4* __restrict__ pred4, const float4* __restrict__ targ4,
    float* __restrict__ P, int rows_per_block)   // rows_per_block % 4 == 0
{
    const int tid = threadIdx.x;
    const int col4 = tid & (C4 - 1);   // which float4 within the row
    const int rowlane = tid >> 7;      // 0..1 (2 rows in flight per block)
    const long long row0 = (long long)blockIdx.x * rows_per_block;

    float4 a_s1 = {0.f, 0.f, 0.f, 0.f};
    float4 a_st = {0.f, 0.f, 0.f, 0.f};
    float4 a_c1 = {0.f, 0.f, 0.f, 0.f};

    for (int r = rowlane; r < rows_per_block; r += 4) {
        size_t i0 = (size_t)(row0 + r) * C4 + col4;
        size_t i1 = (size_t)(row0 + r + 2) * C4 + col4;
        float4 p0 = ntload(pred4 + i0);
        float4 p1 = ntload(pred4 + i1);
        float4 t0 = ntload(targ4 + i0);
        float4 t1 = ntload(targ4 + i1);
        acc4(p0, t0, a_s1, a_st, a_c1);
        acc4(p1, t1, a_s1, a_st, a_c1);
    }

    // Reduce the 2 rowlanes sharing each column-quad, plain coalesced stores.
    __shared__ float4 red[3][256];   // 12 KiB
    red[0][tid] = a_s1;
    red[1][tid] = a_st;
    red[2][tid] = a_c1;
    __syncthreads();
    if (tid < C4) {
        float* slot = P + (size_t)blockIdx.x * PSTRIDE;
        #pragma unroll
        for (int a = 0; a < 3; ++a) {
            float4 v0 = red[a][tid];
            float4 v1 = red[a][tid + 128];
            float4 v;
            v.x = v0.x + v1.x;
            v.y = v0.y + v1.y;
            v.z = v0.z + v1.z;
            v.w = v0.w + v1.w;
            ((float4*)(slot + a * C))[tid] = v;   // coalesced
        }
    }
}

// 128 blocks x 256 threads; block owns one column-quad (4 columns). Thread t
// sums rows t, t+256, ... of P; LDS tree; weights for 4 columns; 1 atomic/block.
__global__ __launch_bounds__(256) void bl_reduce(
    const float* __restrict__ P, const float* __restrict__ pos_prop,
    float* __restrict__ out, int G, float Bf)
{
    const int tid = threadIdx.x;
    const int q = blockIdx.x;            // col-quad 0..127

    float4 s1 = {0,0,0,0}, st = {0,0,0,0}, n1 = {0,0,0,0};
    for (int r = tid; r < G; r += 256) {
        const float* row = P + (size_t)r * PSTRIDE + q * 4;
        float4 a = *(const float4*)(row);
        float4 b = *(const float4*)(row + C);
        float4 c = *(const float4*)(row + 2 * C);
        s1.x += a.x; s1.y += a.y; s1.z += a.z; s1.w += a.w;
        st.x += b.x; st.y += b.y; st.z += b.z; st.w += b.w;
        n1.x += c.x; n1.y += c.y; n1.z += c.z; n1.w += c.w;
    }

    __shared__ float4 red[3][256];   // 12 KiB
    red[0][tid] = s1; red[1][tid] = st; red[2][tid] = n1;
    __syncthreads();

    for (int stride = 128; stride >= 1; stride >>= 1) {
        if (tid < stride) {
            #pragma unroll
            for (int a = 0; a < 3; ++a) {
                float4 u = red[a][tid], v = red[a][tid + stride];
                u.x += v.x; u.y += v.y; u.z += v.z; u.w += v.w;
                red[a][tid] = u;
            }
        }
        __syncthreads();
    }

    if (tid == 0) {
        const float* s1t = (const float*)&red[0][0];
        const float* stt = (const float*)&red[1][0];
        const float* n1t = (const float*)&red[2][0];
        float tot = 0.f;
        #pragma unroll
        for (int j = 0; j < 4; ++j) {
            float s1c = s1t[j], stc = stt[j], n1c = n1t[j];
            float bal = pos_prop[q * 4 + j] * Bf;
            float n0 = Bf - n1c;
            float S0 = stc - s1c;
            float w1, w0;
            if (n1c >= bal) {              // positives are majority
                w1 = bal / n1c;
                w0 = (n0 > 0.f) ? (Bf - bal) / fmaxf(n0, 1.f) : 1.f;
            } else {                       // negatives are majority (n0 > B-bal >= 0)
                w0 = bal / n0;
                w1 = (n1c > 0.f) ? (Bf - bal) / fmaxf(n1c, 1.f) : 1.f;
            }
            tot += w1 * s1c + w0 * S0;
        }
        atomicAdd(out, tot / (Bf * (float)C));   // 128 atomics total
    }
}

extern "C" void kernel_launch(void* const* d_in, const int* in_sizes, int n_in,
                              void* d_out, int out_size, void* d_ws, size_t ws_size,
                              hipStream_t stream) {
    const float* pred     = (const float*)d_in[0];
    const float* target   = (const float*)d_in[1];
    const float* pos_prop = (const float*)d_in[2];
    float* out = (float*)d_out;
    float* P = (float*)d_ws;

    const int Brows = in_sizes[0] / C;     // 65536
    int grid = 4096;                       // P = 4096 * 6 KB = 25 MB
    while ((size_t)grid * PSTRIDE * sizeof(float) > ws_size && grid > 256)
        grid >>= 1;                        // deterministic in ws_size
    const int rpb = Brows / grid;          // 16 rows per block at grid=4096

    (void)hipMemsetAsync(d_out, 0, sizeof(float), stream);
    bl_partial<<<grid, 256, 0, stream>>>((const float4*)pred, (const float4*)target, P, rpb);
    bl_reduce<<<C4, 256, 0, stream>>>(P, pos_prop, out, grid, (float)Brows);
}

// Round 10
// 276.432 us; speedup vs baseline: 1.0790x; 1.0790x over previous
//
#include <hip/hip_runtime.h>
#include <math.h>

// BalancedLoss: B=65536 rows, C=512 classes, pos_prop per class.
// loss = mean(bce(pred,target) * w), w depends only on (column, target value).
//
// Final config (R10): composition of best-measured halves.
//   - bl_partial: block 256 / grid 2048 (rpb 32), nontemporal float4 loads.
//     Measured at the platform streaming-read ceiling (~3.5 TB/s, 268 MB ->
//     <=77us). Evidence: five mechanisms (plain loads R4, register batch R5,
//     global_load_lds DMA R6, occupancy sweep 33->100%, nt loads R8) all
//     converge; grid 4096 (R9) neutral -> stream count not binding.
//   - bl_reduce: 128 blocks x 256 thr, one col-quad per block (~5us at G=2048).
// Fixed, uncontrollable: ~180us harness reset (536MB ws poison at 6.9 TB/s
// write + d_in restore) dominates the reported total.

constexpr int C = 512;
constexpr int C4 = 128;          // float4s per row
constexpr int PSTRIDE = 3 * C;   // 1536 floats per partial slot

typedef float floatv4 __attribute__((ext_vector_type(4)));

__device__ __forceinline__ float softplus_neg_abs(float p) {
    // log(1 + exp(-|p|)) via v_exp/v_log; arg in (1,2], abs err ~1e-7.
    return __logf(1.0f + __expf(-fabsf(p)));
}

__device__ __forceinline__ float4 ntload(const float4* p) {
    floatv4 v = __builtin_nontemporal_load((const floatv4*)p);
    return make_float4(v.x, v.y, v.z, v.w);
}

__device__ __forceinline__ void acc4(const float4& p, const float4& t,
                                     float4& a_s1, float4& a_st, float4& a_c1) {
    float b;
    b = fmaxf(p.x, 0.f) + softplus_neg_abs(p.x) - p.x * t.x;
    a_st.x += b; a_s1.x += b * t.x; a_c1.x += t.x;
    b = fmaxf(p.y, 0.f) + softplus_neg_abs(p.y) - p.y * t.y;
    a_st.y += b; a_s1.y += b * t.y; a_c1.y += t.y;
    b = fmaxf(p.z, 0.f) + softplus_neg_abs(p.z) - p.z * t.z;
    a_st.z += b; a_s1.z += b * t.z; a_c1.z += t.z;
    b = fmaxf(p.w, 0.f) + softplus_neg_abs(p.w) - p.w * t.w;
    a_st.w += b; a_s1.w += b * t.w; a_c1.w += t.w;
}

__global__ __launch_bounds__(256, 8) void bl_partial(
    const float4* __restrict__ pred4, const float4* __restrict__ targ4,
    float* __restrict__ P, int rows_per_block)   // rows_per_block % 4 == 0
{
    const int tid = threadIdx.x;
    const int col4 = tid & (C4 - 1);   // which float4 within the row
    const int rowlane = tid >> 7;      // 0..1 (2 rows in flight per block)
    const long long row0 = (long long)blockIdx.x * rows_per_block;

    float4 a_s1 = {0.f, 0.f, 0.f, 0.f};
    float4 a_st = {0.f, 0.f, 0.f, 0.f};
    float4 a_c1 = {0.f, 0.f, 0.f, 0.f};

    for (int r = rowlane; r < rows_per_block; r += 4) {
        size_t i0 = (size_t)(row0 + r) * C4 + col4;
        size_t i1 = (size_t)(row0 + r + 2) * C4 + col4;
        float4 p0 = ntload(pred4 + i0);
        float4 p1 = ntload(pred4 + i1);
        float4 t0 = ntload(targ4 + i0);
        float4 t1 = ntload(targ4 + i1);
        acc4(p0, t0, a_s1, a_st, a_c1);
        acc4(p1, t1, a_s1, a_st, a_c1);
    }

    // Reduce the 2 rowlanes sharing each column-quad, plain coalesced stores.
    __shared__ float4 red[3][256];   // 12 KiB
    red[0][tid] = a_s1;
    red[1][tid] = a_st;
    red[2][tid] = a_c1;
    __syncthreads();
    if (tid < C4) {
        float* slot = P + (size_t)blockIdx.x * PSTRIDE;
        #pragma unroll
        for (int a = 0; a < 3; ++a) {
            float4 v0 = red[a][tid];
            float4 v1 = red[a][tid + 128];
            float4 v;
            v.x = v0.x + v1.x;
            v.y = v0.y + v1.y;
            v.z = v0.z + v1.z;
            v.w = v0.w + v1.w;
            ((float4*)(slot + a * C))[tid] = v;   // coalesced
        }
    }
}

// 128 blocks x 256 threads; block owns one column-quad (4 columns). Thread t
// sums rows t, t+256, ... of P; LDS tree; weights for 4 columns; 1 atomic/block.
__global__ __launch_bounds__(256) void bl_reduce(
    const float* __restrict__ P, const float* __restrict__ pos_prop,
    float* __restrict__ out, int G, float Bf)
{
    const int tid = threadIdx.x;
    const int q = blockIdx.x;            // col-quad 0..127

    float4 s1 = {0,0,0,0}, st = {0,0,0,0}, n1 = {0,0,0,0};
    for (int r = tid; r < G; r += 256) {
        const float* row = P + (size_t)r * PSTRIDE + q * 4;
        float4 a = *(const float4*)(row);
        float4 b = *(const float4*)(row + C);
        float4 c = *(const float4*)(row + 2 * C);
        s1.x += a.x; s1.y += a.y; s1.z += a.z; s1.w += a.w;
        st.x += b.x; st.y += b.y; st.z += b.z; st.w += b.w;
        n1.x += c.x; n1.y += c.y; n1.z += c.z; n1.w += c.w;
    }

    __shared__ float4 red[3][256];   // 12 KiB
    red[0][tid] = s1; red[1][tid] = st; red[2][tid] = n1;
    __syncthreads();

    for (int stride = 128; stride >= 1; stride >>= 1) {
        if (tid < stride) {
            #pragma unroll
            for (int a = 0; a < 3; ++a) {
                float4 u = red[a][tid], v = red[a][tid + stride];
                u.x += v.x; u.y += v.y; u.z += v.z; u.w += v.w;
                red[a][tid] = u;
            }
        }
        __syncthreads();
    }

    if (tid == 0) {
        const float* s1t = (const float*)&red[0][0];
        const float* stt = (const float*)&red[1][0];
        const float* n1t = (const float*)&red[2][0];
        float tot = 0.f;
        #pragma unroll
        for (int j = 0; j < 4; ++j) {
            float s1c = s1t[j], stc = stt[j], n1c = n1t[j];
            float bal = pos_prop[q * 4 + j] * Bf;
            float n0 = Bf - n1c;
            float S0 = stc - s1c;
            float w1, w0;
            if (n1c >= bal) {              // positives are majority
                w1 = bal / n1c;
                w0 = (n0 > 0.f) ? (Bf - bal) / fmaxf(n0, 1.f) : 1.f;
            } else {                       // negatives are majority (n0 > B-bal >= 0)
                w0 = bal / n0;
                w1 = (n1c > 0.f) ? (Bf - bal) / fmaxf(n1c, 1.f) : 1.f;
            }
            tot += w1 * s1c + w0 * S0;
        }
        atomicAdd(out, tot / (Bf * (float)C));   // 128 atomics total
    }
}

extern "C" void kernel_launch(void* const* d_in, const int* in_sizes, int n_in,
                              void* d_out, int out_size, void* d_ws, size_t ws_size,
                              hipStream_t stream) {
    const float* pred     = (const float*)d_in[0];
    const float* target   = (const float*)d_in[1];
    const float* pos_prop = (const float*)d_in[2];
    float* out = (float*)d_out;
    float* P = (float*)d_ws;

    const int Brows = in_sizes[0] / C;     // 65536
    int grid = 2048;                       // P = 2048 * 6 KB = 12.6 MB
    while ((size_t)grid * PSTRIDE * sizeof(float) > ws_size && grid > 256)
        grid >>= 1;                        // deterministic in ws_size
    const int rpb = Brows / grid;          // 32 rows per block at grid=2048

    (void)hipMemsetAsync(d_out, 0, sizeof(float), stream);
    bl_partial<<<grid, 256, 0, stream>>>((const float4*)pred, (const float4*)target, P, rpb);
    bl_reduce<<<C4, 256, 0, stream>>>(P, pos_prop, out, grid, (float)Brows);
}